// Round 5
// baseline (8184.455 us; speedup 1.0000x reference)
//
#include <hip/hip_runtime.h>
#include <math.h>

// Problem constants
#define NN   307
#define TT   256
#define HHH  64
#define NROW (NN*TT)     // 78592
#define NBLK_D 39        // ceil(307/8) blocks per direction (8 nodes/block)
#define SCANB  78        // total scan blocks (2 directions)

// ---------------- helpers ----------------
__device__ __forceinline__ float wsum(float v){
#pragma unroll
  for (int off = 32; off > 0; off >>= 1) v += __shfl_xor(v, off, 64);
  return v;
}
__device__ __forceinline__ float wsum16(float v){
#pragma unroll
  for (int off = 8; off > 0; off >>= 1) v += __shfl_xor(v, off, 64);
  return v;
}
__device__ __forceinline__ float ftanh(float x){
  x = fminf(20.f, fmaxf(-20.f, x));
  float e = __expf(2.f*x);
  return (e - 1.f)/(e + 1.f);
}
__device__ __forceinline__ float fsigm(float x){ return 1.f/(1.f + __expf(-x)); }

// ---------------- prep kernels ----------------
__global__ void k_sparse(const float* __restrict__ A, int* __restrict__ cnt,
                         int* __restrict__ idx, float* __restrict__ val){
  int n = blockIdx.x*64 + threadIdx.x;
  if (n >= NN) return;
  int c = 0;
  for (int m = 0; m < NN; m++){
    float a = A[n*NN + m];
    if (a != 0.f){ idx[n*NN + c] = m; val[n*NN + c] = a; c++; }
  }
  cnt[n] = c;
}

__global__ void k_tr_cheb(const float* __restrict__ W0, const float* __restrict__ W1,
                          float* __restrict__ W0T, float* __restrict__ W1T){
  int t = blockIdx.x*256 + threadIdx.x;
  if (t >= 2*67*256) return;
  int c = t & 255; int rest = t >> 8; int i = rest % 67; int d = rest / 67;
  int p = c >> 6, o = c & 63;
  int src = ((d*4 + p)*64 + o)*67 + i;
  W0T[t] = W0[src];
  W1T[t] = W1[src];
}

__global__ void k_tr_gru(const float* __restrict__ Wih, const float* __restrict__ Whh,
                         float* __restrict__ WihT, float* __restrict__ WhhT){
  int t = blockIdx.x*256 + threadIdx.x;
  if (t < 2*66*192){
    int j = t % 192; int rest = t / 192; int i = rest % 66; int d = rest / 66;
    WihT[t] = Wih[(d*192 + j)*66 + i];
  }
  if (t < 2*64*192){
    int j = t % 192; int rest = t / 192; int i = rest % 64; int d = rest / 64;
    WhhT[t] = Whh[(d*192 + j)*64 + i];
  }
}

__global__ void k_af(const float* __restrict__ mseq, const float* __restrict__ tfr,
                     const float* __restrict__ tjm, const int* __restrict__ cnt,
                     const int* __restrict__ idx, const float* __restrict__ val,
                     float* __restrict__ AF){
  int n = blockIdx.x, c = blockIdx.y, t = threadIdx.x;
  const float* feat = (c == 0) ? mseq : (c == 1) ? tfr : tjm;
  float acc = 0.f; int k = cnt[n];
  for (int s = 0; s < k; s++) acc += val[n*NN + s] * feat[idx[n*NN + s]*TT + t];
  AF[((size_t)c*NN + n)*TT + t] = acc;
}

// ---------------- recurrent scan: 512 threads, 8 nodes/block, 39 blocks/dir ----
__global__ __launch_bounds__(512, 1)
void k_scan(const float* __restrict__ xseq, const float* __restrict__ mseq,
            const float* __restrict__ tfr, const float* __restrict__ tjm,
            const float* __restrict__ W0T, const float* __restrict__ W1T,
            const float* __restrict__ b0g,
            const float* __restrict__ mixW, const float* __restrict__ mixb,
            const float* __restrict__ WihT, const float* __restrict__ WhhT,
            const float* __restrict__ bih, const float* __restrict__ bhh,
            const float* __restrict__ outW, const float* __restrict__ outb,
            const float* __restrict__ jamW, const float* __restrict__ jamb,
            const int* __restrict__ spcnt, const int* __restrict__ spidx,
            const float* __restrict__ spval, const float* __restrict__ AF,
            float* __restrict__ Hseq, float* __restrict__ PRED, float* __restrict__ JPRED,
            int* __restrict__ slots)
{
  const int tid = threadIdx.x;
  const int bid = blockIdx.x;
  const int d   = bid / NBLK_D;
  const int n0  = (bid % NBLK_D) * 8;
  const int lane = tid & 63;
  const int wid  = tid >> 6;          // 0..7 = row
  const int half = tid >> 8;          // 0..1 (phase 3 row-quad)
  const int t255 = tid & 255;

  __shared__ __align__(16) float hsT[68][8];
  __shared__ __align__(16) float amsT[68][8];
  __shared__ __align__(16) float msgsT[64][8];
  __shared__ __align__(16) float malls[256][8];
  __shared__ float gis[8][192];
  __shared__ float ghs[8][192];
  __shared__ float mixs[4][8];
  __shared__ float xss[8], mss[8];
  __shared__ int   s_idx[8][320];
  __shared__ float s_val[8][320];
  __shared__ int   s_cnt[8];

  // -------- weight preload (dup across halves; read once, reused 256 steps) ----
  float w0r[67], w1r[67];
#pragma unroll
  for (int i = 0; i < 67; i++){
    w0r[i] = W0T[(d*67 + i)*256 + t255];
    w1r[i] = W1T[(d*67 + i)*256 + t255];
  }
  const float b0r = b0g[d*256 + t255];
  float wih_r[64], whh_r[64];
  float wih64 = 0.f, wih65 = 0.f, bih_r = 0.f, bhh_r = 0.f;
  const int rq = (tid >= 192) ? 1 : 0;          // row-quad for phase 4 (tid<384)
  const int gj = tid - rq*192;                  // gate column j
  if (tid < 384){
#pragma unroll
    for (int i = 0; i < 64; i++){
      whh_r[i] = WhhT[(d*64 + i)*192 + gj];
      wih_r[i] = WihT[(d*66 + i)*192 + gj];
    }
    wih64 = WihT[(d*66 + 64)*192 + gj];
    wih65 = WihT[(d*66 + 65)*192 + gj];
    bih_r = bih[d*192 + gj];
    bhh_r = bhh[d*192 + gj];
  }
  float mixw_r[4];
#pragma unroll
  for (int p = 0; p < 4; p++) mixw_r[p] = mixW[(d*4 + p)*64 + lane];
  const float mixb_r[4] = {mixb[d*4+0], mixb[d*4+1], mixb[d*4+2], mixb[d*4+3]};
  const float outw_r = outW[d*64 + lane], jamw_r = jamW[d*64 + lane];
  const float outb_r = outb[d], jamb_r = jamb[d];

  // -------- sparse neighbor lists into LDS (padded to x16); zero h --------
  for (int r = 0; r < 8; r++){
    const int n = min(n0 + r, NN-1);
    const int cc = spcnt[n];
    const int ccp = (cc + 15) & ~15;
    if (tid == 0) s_cnt[r] = ccp;
    for (int s = tid; s < ccp; s += 512){
      s_idx[r][s] = (s < cc) ? spidx[n*NN + s] : 0;
      s_val[r][s] = (s < cc) ? spval[n*NN + s] : 0.f;
    }
  }
  hsT[lane][wid] = 0.f;
  __syncthreads();

#pragma unroll 1
  for (int k = 0; k < TT; k++){
    const int ts = (d == 0) ? k : (TT-1 - k);
    // phase 0: time-step scalars
    if (tid < 8){
      const int r = tid; const int n = min(n0 + r, NN-1);
      const float mv = mseq[n*TT + ts];
      hsT[64][r] = mv;
      hsT[65][r] = tfr[n*TT + ts];
      hsT[66][r] = tjm[n*TT + ts];
      amsT[64][r] = AF[(0*NN + n)*TT + ts];
      amsT[65][r] = AF[(1*NN + n)*TT + ts];
      amsT[66][r] = AF[(2*NN + n)*TT + ts];
      xss[r] = xseq[n*TT + ts];
      mss[r] = mv;
    }
    // phase 1: am = sparse Anorm @ h_prev (lane = feature, wave = row)
    {
      const float* Hprev = Hseq + (size_t)(d*257 + k)*NN*64;
      const int r = wid;
      const int ccp = s_cnt[r];
      float acc = 0.f;
      for (int s = 0; s < ccp; s += 16){
        float aV[16], hV[16];
#pragma unroll
        for (int u = 0; u < 16; u++){
          const int m = s_idx[r][s+u];
          aV[u] = s_val[r][s+u];
          hV[u] = __hip_atomic_load(&Hprev[(size_t)m*64 + lane],
                                    __ATOMIC_RELAXED, __HIP_MEMORY_SCOPE_AGENT);
        }
#pragma unroll
        for (int u = 0; u < 16; u++) acc += aV[u]*hV[u];
      }
      amsT[lane][r] = acc;
    }
    // phase 2: mix = softmax(h @ mixW^T + mixb) (wave = row)
    {
      const int r = wid;
      const float hv = hsT[lane][r];
      float l0 = wsum(hv * mixw_r[0]) + mixb_r[0];
      float l1 = wsum(hv * mixw_r[1]) + mixb_r[1];
      float l2 = wsum(hv * mixw_r[2]) + mixb_r[2];
      float l3 = wsum(hv * mixw_r[3]) + mixb_r[3];
      const float mx = fmaxf(fmaxf(l0,l1), fmaxf(l2,l3));
      const float e0 = __expf(l0-mx), e1 = __expf(l1-mx), e2 = __expf(l2-mx), e3 = __expf(l3-mx);
      const float inv = 1.f/(e0+e1+e2+e3);
      if (lane == 0){
        mixs[0][r] = e0*inv; mixs[1][r] = e1*inv; mixs[2][r] = e2*inv; mixs[3][r] = e3*inv;
      }
    }
    __syncthreads();
    // phase 3: m_all = tanh(msg_in@W0^T + am@W1^T + b0), scaled by mix
    // thread = (half, p, o); rows half*4..half*4+3
    {
      const int p = (tid >> 6) & 3;
      float a0 = b0r, a1 = b0r, a2 = b0r, a3 = b0r;
#pragma unroll
      for (int i = 0; i < 67; i++){
        const float4 h4 = *(const float4*)&hsT[i][half*4];
        const float4 m4 = *(const float4*)&amsT[i][half*4];
        const float w0 = w0r[i], w1 = w1r[i];
        a0 += h4.x*w0 + m4.x*w1;
        a1 += h4.y*w0 + m4.y*w1;
        a2 += h4.z*w0 + m4.z*w1;
        a3 += h4.w*w0 + m4.w*w1;
      }
      float4 mo;
      mo.x = mixs[p][half*4+0]*ftanh(a0);
      mo.y = mixs[p][half*4+1]*ftanh(a1);
      mo.z = mixs[p][half*4+2]*ftanh(a2);
      mo.w = mixs[p][half*4+3]*ftanh(a3);
      *(float4*)&malls[t255][half*4] = mo;
    }
    __syncthreads();
    // phase 3b: msg = sum_p m_all[p][:]
    msgsT[lane][wid] = malls[lane][wid] + malls[64+lane][wid] + malls[128+lane][wid] + malls[192+lane][wid];
    __syncthreads();
    // phase 4: gi, gh (thread = (rq, gate column j)); rows rq*4..rq*4+3
    if (tid < 384){
      float g0 = bhh_r, g1 = bhh_r, g2 = bhh_r, g3 = bhh_r;
#pragma unroll
      for (int i = 0; i < 64; i++){
        const float4 h4 = *(const float4*)&hsT[i][rq*4];
        const float w = whh_r[i];
        g0 += h4.x*w; g1 += h4.y*w; g2 += h4.z*w; g3 += h4.w*w;
      }
      ghs[rq*4+0][gj] = g0; ghs[rq*4+1][gj] = g1; ghs[rq*4+2][gj] = g2; ghs[rq*4+3][gj] = g3;
      float q0 = bih_r + (xss[rq*4+0]*mss[rq*4+0])*wih64 + mss[rq*4+0]*wih65;
      float q1 = bih_r + (xss[rq*4+1]*mss[rq*4+1])*wih64 + mss[rq*4+1]*wih65;
      float q2 = bih_r + (xss[rq*4+2]*mss[rq*4+2])*wih64 + mss[rq*4+2]*wih65;
      float q3 = bih_r + (xss[rq*4+3]*mss[rq*4+3])*wih64 + mss[rq*4+3]*wih65;
#pragma unroll
      for (int i = 0; i < 64; i++){
        const float4 m4 = *(const float4*)&msgsT[i][rq*4];
        const float w = wih_r[i];
        q0 += m4.x*w; q1 += m4.y*w; q2 += m4.z*w; q3 += m4.w*w;
      }
      gis[rq*4+0][gj] = q0; gis[rq*4+1][gj] = q1; gis[rq*4+2][gj] = q2; gis[rq*4+3][gj] = q3;
    }
    __syncthreads();
    // phase 5: GRU update + write-through h store (agent scope)
    {
      const int r = wid, o = lane;
      const float ir = gis[r][o], iz = gis[r][o+64], in_ = gis[r][o+128];
      const float hr = ghs[r][o], hz = ghs[r][o+64], hn = ghs[r][o+128];
      const float rr2 = fsigm(ir + hr);
      const float zz = fsigm(iz + hz);
      const float nnv = ftanh(in_ + rr2*hn);
      const float hold = hsT[o][r];
      const float h2 = (1.f - zz)*nnv + zz*hold + 0.1f*hold;
      hsT[o][r] = h2;
      const int n = n0 + r;
      if (n < NN)
        __hip_atomic_store(&Hseq[((size_t)(d*257 + k + 1)*NN + n)*64 + o], h2,
                           __ATOMIC_RELAXED, __HIP_MEMORY_SCOPE_AGENT);
    }
    __syncthreads();   // all waves' h stores drained (vmcnt(0) before s_barrier)
    // arrive: publish own flag ASAP
    if (tid == 0)
      __hip_atomic_store(&slots[bid], k + 1, __ATOMIC_RELAXED, __HIP_MEMORY_SCOPE_AGENT);
    // phase 6: pred/jam (overlaps flag visibility latency)
    {
      const float h2 = hsT[lane][wid];
      const float pv = wsum(h2 * outw_r);
      const float jv = wsum(h2 * jamw_r);
      const int n = n0 + wid;
      if (lane == 0 && n < NN){
        PRED [(d*NN + n)*TT + ts] = pv + outb_r;
        JPRED[(d*NN + n)*TT + ts] = jv + jamb_r;
      }
    }
    // wait: wave 0 lane-parallel poll of this direction's 39 flags (1 coalesced load)
    if (tid < 64){
      const int* sl = slots + d*NBLK_D;
      for (;;){
        const int a = (lane < NBLK_D)
            ? __hip_atomic_load(&sl[lane], __ATOMIC_RELAXED, __HIP_MEMORY_SCOPE_AGENT)
            : 0x7fffffff;
        if (__all(a >= k + 1)) break;
        __builtin_amdgcn_s_sleep(1);
      }
    }
    __syncthreads();
  }
}

// ---------------- fusion: weights, cell outputs (x0.7), h_fused + pos-enc ----------------
__global__ __launch_bounds__(256)
void k_fusion(const float* __restrict__ PRED, const float* __restrict__ JPRED,
              const float* __restrict__ Hseq,
              const float* __restrict__ fw1, const float* __restrict__ fb1,
              const float* __restrict__ fw2, const float* __restrict__ fb2,
              float* __restrict__ x0, float* __restrict__ outp)
{
  const int tid = threadIdx.x;
  const int rr = tid >> 6, lane = tid & 63;
  const int idx = blockIdx.x*4 + rr;
  const int n = idx >> 8, t = idx & 255;
  const float pf = PRED[(0*NN + n)*TT + t], pb = PRED[(NN + n)*TT + t];
  const float jf = JPRED[(0*NN + n)*TT + t], jb = JPRED[(NN + n)*TT + t];
  const float hid = fmaxf(fw1[lane*2]*pf + fw1[lane*2+1]*pb + fb1[lane], 0.f);
  const float l0 = wsum(hid * fw2[lane]) + fb2[0];
  const float l1 = wsum(hid * fw2[64+lane]) + fb2[1];
  const float mx = fmaxf(l0,l1);
  const float e0 = __expf(l0-mx), e1 = __expf(l1-mx);
  const float inv = 1.f/(e0+e1);
  const float w0 = e0*inv, w1 = e1*inv;
  const float hf = Hseq[((size_t)(0*257 + t + 1)*NN + n)*64 + lane];
  const float hb = Hseq[((size_t)(257 + 256 - t)*NN + n)*64 + lane];
  const int i2 = lane & ~1;
  const float dv = powf(10000.f, (float)i2 * (1.f/64.f));
  const float arg = (float)t / dv;
  const float pe = (lane & 1) ? cosf(arg) : sinf(arg);
  x0[(size_t)idx*64 + lane] = hf*w0 + hb*w1 + pe;
  if (lane == 0){
    outp[idx]        = 0.7f*(w0*pf + w1*pb);
    outp[NROW + idx] = 0.7f*(w0*jf + w1*jb);
  }
}

// ---------------- tiled fp32 GEMM: Y = act(X @ W^T + b) ----------------
__global__ __launch_bounds__(256)
void k_linear(const float* __restrict__ X, const float* __restrict__ W,
              const float* __restrict__ bias, float* __restrict__ Y,
              int K, int Nout, int act)
{
  __shared__ __align__(16) float Xs[64][68];
  __shared__ __align__(16) float Ws[64][68];
  const int tid = threadIdx.x;
  const int tx = tid & 15, ty = tid >> 4;
  const int brow = blockIdx.x*64, bcol = blockIdx.y*64;
  float acc[4][4] = {};
  for (int k0 = 0; k0 < K; k0 += 64){
    for (int i = tid; i < 64*64; i += 256){
      const int r = i >> 6, c = i & 63;
      Xs[r][c] = X[(size_t)(brow + r)*K + k0 + c];
      Ws[r][c] = W[(size_t)(bcol + r)*K + k0 + c];
    }
    __syncthreads();
#pragma unroll
    for (int kk = 0; kk < 64; kk += 4){
      float4 xv[4], wv[4];
#pragma unroll
      for (int i = 0; i < 4; i++) xv[i] = *(const float4*)&Xs[ty + 16*i][kk];
#pragma unroll
      for (int j = 0; j < 4; j++) wv[j] = *(const float4*)&Ws[tx + 16*j][kk];
#pragma unroll
      for (int i = 0; i < 4; i++)
#pragma unroll
        for (int j = 0; j < 4; j++)
          acc[i][j] += xv[i].x*wv[j].x + xv[i].y*wv[j].y + xv[i].z*wv[j].z + xv[i].w*wv[j].w;
    }
    __syncthreads();
  }
#pragma unroll
  for (int i = 0; i < 4; i++){
    const int gr = brow + ty + 16*i;
#pragma unroll
    for (int j = 0; j < 4; j++){
      const int gc = bcol + tx + 16*j;
      float v = acc[i][j] + bias[gc];
      if (act) v = fmaxf(v, 0.f);
      Y[(size_t)gr*Nout + gc] = v;
    }
  }
}

// ------- fp32 GEMM (Nout=64) + residual + LayerNorm fused epilogue -------
__global__ __launch_bounds__(256)
void k_linear_ln(const float* __restrict__ X, const float* __restrict__ W,
                 const float* __restrict__ bias, const float* __restrict__ Xres,
                 const float* __restrict__ g, const float* __restrict__ b,
                 float* __restrict__ Y, int K)
{
  __shared__ __align__(16) float Xs[64][68];
  __shared__ __align__(16) float Ws[64][68];
  const int tid = threadIdx.x;
  const int tx = tid & 15, ty = tid >> 4;
  const int brow = blockIdx.x*64;
  float acc[4][4] = {};
  for (int k0 = 0; k0 < K; k0 += 64){
    for (int i = tid; i < 64*64; i += 256){
      const int r = i >> 6, c = i & 63;
      Xs[r][c] = X[(size_t)(brow + r)*K + k0 + c];
      Ws[r][c] = W[(size_t)r*K + k0 + c];
    }
    __syncthreads();
#pragma unroll
    for (int kk = 0; kk < 64; kk += 4){
      float4 xv[4], wv[4];
#pragma unroll
      for (int i = 0; i < 4; i++) xv[i] = *(const float4*)&Xs[ty + 16*i][kk];
#pragma unroll
      for (int j = 0; j < 4; j++) wv[j] = *(const float4*)&Ws[tx + 16*j][kk];
#pragma unroll
      for (int i = 0; i < 4; i++)
#pragma unroll
        for (int j = 0; j < 4; j++)
          acc[i][j] += xv[i].x*wv[j].x + xv[i].y*wv[j].y + xv[i].z*wv[j].z + xv[i].w*wv[j].w;
    }
    __syncthreads();
  }
  // epilogue: v = acc + bias + residual; LN over the 64-wide row (16 lanes x 4 cols)
#pragma unroll
  for (int i = 0; i < 4; i++){
    const int gr = brow + ty + 16*i;
    float v[4];
    float s = 0.f;
#pragma unroll
    for (int j = 0; j < 4; j++){
      const int gc = tx + 16*j;
      v[j] = acc[i][j] + bias[gc] + Xres[(size_t)gr*64 + gc];
      s += v[j];
    }
    const float mu = wsum16(s) * (1.f/64.f);
    float vs = 0.f;
#pragma unroll
    for (int j = 0; j < 4; j++){ v[j] -= mu; vs += v[j]*v[j]; }
    const float rstd = rsqrtf(wsum16(vs) * (1.f/64.f) + 1e-5f);
#pragma unroll
    for (int j = 0; j < 4; j++){
      const int gc = tx + 16*j;
      Y[(size_t)gr*64 + gc] = v[j] * rstd * g[gc] + b[gc];
    }
  }
}

// ------- attention per (node, head): coalesced staging + online softmax -------
__global__ __launch_bounds__(256)
void k_attn(const float* __restrict__ QKV, float* __restrict__ O)
{
  const int n = blockIdx.x, h = blockIdx.y;
  const int tid = threadIdx.x;
  __shared__ __align__(16) float Ks[256][20];   // +4 pad: conflict-free
  __shared__ __align__(16) float Vs[256][20];
  const float* nbase = QKV + (size_t)n*256*192;
  // staging: thread covers (t = tid>>3, part = tid&7); parts 0-3 = K slice (64B
  // contiguous per 4 lanes), parts 4-7 = V slice. 8 passes cover t in [0,256).
  {
    const int part = tid & 7;
    const int kv = part >> 2;          // 0 = K, 1 = V
    const int c4 = (part & 3) * 4;     // col within 16-float slice
#pragma unroll
    for (int p = 0; p < 8; p++){
      const int t = p*32 + (tid >> 3);
      const float4 v4 = *(const float4*)(nbase + (size_t)t*192 + 64 + kv*64 + h*16 + c4);
      if (kv == 0) *(float4*)&Ks[t][c4] = v4;
      else         *(float4*)&Vs[t][c4] = v4;
    }
  }
  float q[16];
  {
    const float4* qs = (const float4*)(nbase + (size_t)tid*192 + h*16);
#pragma unroll
    for (int c = 0; c < 4; c++){
      float4 t4 = qs[c];
      q[c*4+0]=t4.x*0.25f; q[c*4+1]=t4.y*0.25f; q[c*4+2]=t4.z*0.25f; q[c*4+3]=t4.w*0.25f;
    }
  }
  __syncthreads();
  float m = -1e30f, l = 0.f, acc[16] = {};
  for (int j = 0; j < 256; j++){
    float s = 0.f;
#pragma unroll
    for (int dd = 0; dd < 16; dd++) s += q[dd]*Ks[j][dd];
    const float mn = fmaxf(m, s);
    const float corr = __expf(m - mn);
    const float p = __expf(s - mn);
    l = l*corr + p;
#pragma unroll
    for (int dd = 0; dd < 16; dd++) acc[dd] = acc[dd]*corr + p*Vs[j][dd];
    m = mn;
  }
  const float inv = 1.f/l;
  float* orow = O + ((size_t)n*256 + tid)*64 + h*16;
#pragma unroll
  for (int dd = 0; dd < 16; dd++) orow[dd] = acc[dd]*inv;
}

// ---------------- final projection, out += 0.3*refined ----------------
__global__ __launch_bounds__(256)
void k_proj_add(const float* __restrict__ X, const float* __restrict__ pW,
                const float* __restrict__ pb, float* __restrict__ outp)
{
  const int tid = threadIdx.x;
  const int r = tid >> 6, lane = tid & 63;
  const size_t row = (size_t)blockIdx.x*4 + r;
  const float v = X[row*64 + lane] * pW[lane];
  const float s = wsum(v);
  if (lane == 0) outp[row] += 0.3f*(s + pb[0]);
}

// ---------------- host launcher ----------------
extern "C" void kernel_launch(void* const* d_in, const int* in_sizes, int n_in,
                              void* d_out, int out_size, void* d_ws, size_t ws_size,
                              hipStream_t stream)
{
  const float* x_seq = (const float*)d_in[0];
  const float* m_seq = (const float*)d_in[1];
  const float* tod_f = (const float*)d_in[2];
  const float* tod_j = (const float*)d_in[3];
  const float* Anorm = (const float*)d_in[4];
  const float* chW0  = (const float*)d_in[5];
  const float* chb0  = (const float*)d_in[6];
  const float* chW1  = (const float*)d_in[7];
  const float* mixW  = (const float*)d_in[8];
  const float* mixb  = (const float*)d_in[9];
  const float* Wih   = (const float*)d_in[10];
  const float* Whh   = (const float*)d_in[11];
  const float* bih   = (const float*)d_in[12];
  const float* bhh   = (const float*)d_in[13];
  const float* outW  = (const float*)d_in[14];
  const float* outbp = (const float*)d_in[15];
  const float* jamW  = (const float*)d_in[16];
  const float* jambp = (const float*)d_in[17];
  const float* fW1   = (const float*)d_in[18];
  const float* fb1   = (const float*)d_in[19];
  const float* fW2   = (const float*)d_in[20];
  const float* fb2   = (const float*)d_in[21];
  const float* qkvW  = (const float*)d_in[22];
  const float* qkvb  = (const float*)d_in[23];
  const float* oW    = (const float*)d_in[24];
  const float* ob    = (const float*)d_in[25];
  const float* ln1g  = (const float*)d_in[26];
  const float* ln1b  = (const float*)d_in[27];
  const float* f1W   = (const float*)d_in[28];
  const float* f1b   = (const float*)d_in[29];
  const float* f2W   = (const float*)d_in[30];
  const float* f2b   = (const float*)d_in[31];
  const float* ln2g  = (const float*)d_in[32];
  const float* ln2b  = (const float*)d_in[33];
  const float* prW   = (const float*)d_in[34];
  const float* prb   = (const float*)d_in[35];
  float* out = (float*)d_out;

  float* ws = (float*)d_ws;
  size_t off = 0;
  auto take = [&](size_t n)->float*{ float* p = ws + off; off += (n + 63) & ~(size_t)63; return p; };
  int*   slots = (int*)take(256);
  float* W0T  = take((size_t)2*67*256);
  float* W1T  = take((size_t)2*67*256);
  float* WihT = take((size_t)2*66*192);
  float* WhhT = take((size_t)2*64*192);
  int*   spcnt = (int*)take(320);
  int*   spidx = (int*)take((size_t)NN*NN);
  float* spval = take((size_t)NN*NN);
  float* AF    = take((size_t)3*NN*TT);
  float* PRED  = take((size_t)2*NN*TT);
  float* JPRED = take((size_t)2*NN*TT);
  float* HSEQ  = take((size_t)2*257*NN*64);
  float* X0    = take((size_t)NROW*64);
  float* XBUF  = take((size_t)NROW*64);
  float* OBUF  = take((size_t)NROW*64);
  float* FBUF  = take((size_t)NROW*256);   // holds QKV (192) and FF1 out (256)
  (void)ws_size; (void)in_sizes; (void)n_in; (void)out_size;

  hipMemsetAsync(slots, 0, 256*sizeof(int), stream);
  hipMemsetAsync(HSEQ, 0, (size_t)NN*64*sizeof(float), stream);                     // h0 fwd
  hipMemsetAsync(HSEQ + (size_t)257*NN*64, 0, (size_t)NN*64*sizeof(float), stream); // h0 bwd

  k_sparse<<<dim3((NN+63)/64), dim3(64), 0, stream>>>(Anorm, spcnt, spidx, spval);
  k_tr_cheb<<<dim3(134), dim3(256), 0, stream>>>(chW0, chW1, W0T, W1T);
  k_tr_gru<<<dim3(99), dim3(256), 0, stream>>>(Wih, Whh, WihT, WhhT);
  k_af<<<dim3(NN,3), dim3(256), 0, stream>>>(m_seq, tod_f, tod_j, spcnt, spidx, spval, AF);

  k_scan<<<dim3(SCANB), dim3(512), 0, stream>>>(x_seq, m_seq, tod_f, tod_j, W0T, W1T,
      chb0, mixW, mixb, WihT, WhhT, bih, bhh, outW, outbp, jamW, jambp,
      spcnt, spidx, spval, AF, HSEQ, PRED, JPRED, slots);

  k_fusion<<<dim3(NROW/4), dim3(256), 0, stream>>>(PRED, JPRED, HSEQ, fW1, fb1, fW2, fb2, X0, out);

  for (int e = 0; e < 2; e++){
    for (int l = 0; l < 3; l++){
      const int el = e*3 + l;
      const float* xin = (l == 0) ? X0 : XBUF;
      // qkv: (NROW,64) @ (192,64)^T -> FBUF (192-wide)
      k_linear<<<dim3(NROW/64, 3), dim3(256), 0, stream>>>(xin, qkvW + (size_t)el*192*64,
          qkvb + (size_t)el*192, FBUF, 64, 192, 0);
      k_attn<<<dim3(NN, 4), dim3(256), 0, stream>>>(FBUF, OBUF);
      // oproj + residual + LN1 -> XBUF
      k_linear_ln<<<dim3(NROW/64), dim3(256), 0, stream>>>(OBUF, oW + (size_t)el*64*64,
          ob + (size_t)el*64, xin, ln1g + (size_t)el*64, ln1b + (size_t)el*64, XBUF, 64);
      // ff1: (NROW,64) @ (256,64)^T -> FBUF (256-wide, relu)
      k_linear<<<dim3(NROW/64, 4), dim3(256), 0, stream>>>(XBUF, f1W + (size_t)el*256*64,
          f1b + (size_t)el*256, FBUF, 64, 256, 1);
      // ff2 + residual + LN2 -> XBUF (element-wise in-place safe)
      k_linear_ln<<<dim3(NROW/64), dim3(256), 0, stream>>>(FBUF, f2W + (size_t)el*64*256,
          f2b + (size_t)el*64, XBUF, ln2g + (size_t)el*64, ln2b + (size_t)el*64, XBUF, 256);
    }
    k_proj_add<<<dim3(NROW/4), dim3(256), 0, stream>>>(XBUF, prW + (size_t)e*64, prb + e,
        out + (size_t)e*NROW);
  }
}